// Round 12
// baseline (271.141 us; speedup 1.0000x reference)
//
#include <hip/hip_runtime.h>
#include <hip/hip_bf16.h>

#define N_SAMP    32768
#define NBINS     16384
#define NSIG      16
#define NBANDS    7
#define K_TOP     128
// padded per-signal band buffer: 64 zero-floats of guard before each band
#define BAND_STRIDE 65472   // 448 pad + 65024 payload

// staged bf16 layout (small): [filters 4096 | PT 8192 | PF 8192]
#define SST_F   0
#define SST_PT  4096
#define SST_PF  12288
#define SST_TOT 20480

#define TWO_PI 6.283185307179586f

typedef __attribute__((ext_vector_type(8))) short bf16x8;
typedef __attribute__((ext_vector_type(4))) float f32x4;

__device__ __forceinline__ float bf2f(__hip_bfloat16 v) { return __bfloat162float(v); }

__device__ __forceinline__ unsigned encf(float f) {
    unsigned u = __float_as_uint(f);
    return (u & 0x80000000u) ? ~u : (u | 0x80000000u);
}
__device__ __forceinline__ float decf(unsigned u) {
    return __uint_as_float((u & 0x80000000u) ? (u ^ 0x80000000u) : ~u);
}

__device__ __forceinline__ int band_M1sh(int b) { return b < 3 ? 4 : (b < 4 ? 5 : 6); }
__device__ __forceinline__ int band_Lsh(int b) {
    return b == 0 ? 5 : (b == 1 ? 6 : (b < 5 ? 7 : (b == 5 ? 8 : 9)));
}
__device__ __forceinline__ int band_M2sh(int b) {
    return b < 2 ? 4 : (b < 5 ? 5 : (b == 5 ? 6 : 7));
}

// ---------------------------------------------------------------------------
// K_stage (small): stage filters/PT/PF to bf16; tail block zeroes guards +
// accum + counter. Per-block dtype detect (proven r7).
__global__ __launch_bounds__(256) void k_stage(
    const void* __restrict__ t, const void* __restrict__ f,
    const void* __restrict__ pt, const void* __restrict__ pf,
    __hip_bfloat16* __restrict__ staged,
    float* __restrict__ bands, float* __restrict__ accum,
    int* __restrict__ counter)
{
    const int tid = threadIdx.x;
    const int bx  = blockIdx.x;
    if (bx == SST_TOT / 256) {                 // init block
        for (int i = tid; i < NSIG * 448; i += 256) {
            int sig = i / 448, rem = i - sig * 448;
            int g = rem >> 6, j = rem & 63;
            int off = 64 * g + 512 * ((1 << g) - 1);
            bands[(size_t)sig * BAND_STRIDE + off + j] = 0.f;
        }
        if (tid == 0) { accum[0] = 0.f; counter[0] = 0; }
        return;
    }
    float pv = bf2f(((const __hip_bfloat16*)t)[tid & 63]);
    int bad = (fabsf(pv) > 1e8f) || (pv != pv);
    const int isf32 = (__ballot(bad) != 0ull);
    const int id = bx * 256 + tid;
    const void* src; int idx;
    if (id < SST_PT)      { src = f;  idx = id; }
    else if (id < SST_PF) { src = pt; idx = id - SST_PT; }
    else                  { src = pf; idx = id - SST_PF; }
    float v = isf32 ? ((const float*)src)[idx]
                    : bf2f(((const __hip_bfloat16*)src)[idx]);
    staged[id] = __float2bfloat16(v);
}

// ---------------------------------------------------------------------------
// K_fwd1 — MFMA version. A[k1][n2] = sum_n1 W128[k1][n1] * x[n1][n2] as a
// 128x(128 n2-half)x128 GEMM. W split Whi+Wlo (bf16 pair, residual <=2^-18)
// for fp32-grade accuracy; x staged TRANSPOSED in LDS (pitch 136 elems ->
// aligned b128 B-frags, conflict-free). Epilogue: T = A * e^{-2pi i n2 k1/N}.
__global__ __launch_bounds__(256) void k_fwd1(
    const void* __restrict__ tgt, const void* __restrict__ rec,
    float* __restrict__ T)
{
    const int tid   = threadIdx.x;
    const int sig   = blockIdx.y;
    const int nbase = blockIdx.x * 128;        // n2 half
    __shared__ __align__(16) __hip_bfloat16 xT[128][136];  // [n2-local][n1]

    float pv = bf2f(((const __hip_bfloat16*)tgt)[tid & 63]);
    int bad = (fabsf(pv) > 1e8f) || (pv != pv);
    const int isf32 = (__ballot(bad) != 0ull);
    const void* xsrc = (sig < 8) ? tgt : rec;
    const int soff = (sig & 7) * N_SAMP;

    // stage transpose: row rloc = n2-local, thread covers one col half
    const int rloc = tid & 127;
    const int chb  = (tid >> 7) * 64;
    for (int c8 = 0; c8 < 64; c8 += 8) {
        union { bf16x8 v; __hip_bfloat16 h[8]; } u;
        #pragma unroll
        for (int uu = 0; uu < 8; ++uu) {
            int n1 = chb + c8 + uu;
            int gi = soff + n1 * 256 + nbase + rloc;
            float xv = isf32 ? ((const float*)xsrc)[gi]
                             : bf2f(((const __hip_bfloat16*)xsrc)[gi]);
            u.h[uu] = __float2bfloat16(xv);
        }
        *(bf16x8*)(&xT[rloc][chb + c8]) = u.v;
    }
    __syncthreads();

    const int tl = tid & 15, quad = (tid >> 4) & 3, w = tid >> 6;
    // A-frags for mi in {2w, 2w+1}: W[k1][n1] = e^{-2pi i (k1 n1 mod 128)/128}
    bf16x8 Arh[2][4], Arl[2][4], Aih[2][4], Ail[2][4];
    #pragma unroll
    for (int m2 = 0; m2 < 2; ++m2) {
        int k1 = (2 * w + m2) * 16 + tl;       // A row m = lane&15
        #pragma unroll
        for (int ki = 0; ki < 4; ++ki) {
            union { bf16x8 v; __hip_bfloat16 h[8]; } rh, rl, ih, il;
            #pragma unroll
            for (int j = 0; j < 8; ++j) {
                int n1 = ki * 32 + quad * 8 + j;
                int tt = (k1 * n1) & 127;
                float sv, cv;
                sincosf(TWO_PI * (float)tt * (1.f / 128.f), &sv, &cv);
                float wre = cv, wim = -sv;     // e^{-ia}
                __hip_bfloat16 h1 = __float2bfloat16(wre);
                rh.h[j] = h1;
                rl.h[j] = __float2bfloat16(wre - bf2f(h1));
                __hip_bfloat16 h2 = __float2bfloat16(wim);
                ih.h[j] = h2;
                il.h[j] = __float2bfloat16(wim - bf2f(h2));
            }
            Arh[m2][ki] = rh.v; Arl[m2][ki] = rl.v;
            Aih[m2][ki] = ih.v; Ail[m2][ki] = il.v;
        }
    }

    float2* To = (float2*)T + (size_t)sig * 128 * 256;
    for (int ni = 0; ni < 8; ++ni) {
        bf16x8 B[4];
        #pragma unroll
        for (int ki = 0; ki < 4; ++ki)         // B[k=n1][n=n2]: b128, aligned
            B[ki] = *(const bf16x8*)(&xT[ni * 16 + tl][ki * 32 + quad * 8]);
        #pragma unroll
        for (int m2 = 0; m2 < 2; ++m2) {
            f32x4 aR = {0.f,0.f,0.f,0.f}, aI = {0.f,0.f,0.f,0.f};
            #pragma unroll
            for (int ki = 0; ki < 4; ++ki) {
                aR = __builtin_amdgcn_mfma_f32_16x16x32_bf16(Arh[m2][ki], B[ki], aR, 0, 0, 0);
                aR = __builtin_amdgcn_mfma_f32_16x16x32_bf16(Arl[m2][ki], B[ki], aR, 0, 0, 0);
                aI = __builtin_amdgcn_mfma_f32_16x16x32_bf16(Aih[m2][ki], B[ki], aI, 0, 0, 0);
                aI = __builtin_amdgcn_mfma_f32_16x16x32_bf16(Ail[m2][ki], B[ki], aI, 0, 0, 0);
            }
            const int n2 = nbase + ni * 16 + tl;
            const int mk = (2 * w + m2) * 16 + quad * 4;  // D row = quad*4+reg
            #pragma unroll
            for (int rg = 0; rg < 4; ++rg) {
                int k1e = mk + rg;
                float sv, cv;                  // e^{-i th}: Tr=ar*cv+ai*sv
                sincosf((TWO_PI / 32768.f) * (float)(k1e * n2), &sv, &cv);
                float Tr = aR[rg] * cv + aI[rg] * sv;
                float Ti = aI[rg] * cv - aR[rg] * sv;
                To[(size_t)k1e * 256 + n2] = make_float2(Tr, Ti);
            }
        }
    }
}

// Step2 with 4 independent rotation chains (proven r10)
__global__ __launch_bounds__(128) void k_fwd2(
    const float* __restrict__ T, float* __restrict__ C)
{
    const int k2  = threadIdx.x;              // < 128
    const int k1  = blockIdx.x;
    const int sig = blockIdx.y;
    __shared__ float2 Ts[256];
    const float2* Tin = (const float2*)T + ((size_t)sig * 128 + k1) * 256;
    for (int i = k2; i < 256; i += 128) Ts[i] = Tin[i];
    __syncthreads();
    float er[4], ei[4];
    #pragma unroll
    for (int c = 0; c < 4; ++c) {
        float sv, cv;
        sincosf(-TWO_PI * (float)((c * k2) & 255) * (1.f / 256.f), &sv, &cv);
        er[c] = cv; ei[c] = sv;
    }
    float s4, c4;
    sincosf(-TWO_PI * (float)((4 * k2) & 255) * (1.f / 256.f), &s4, &c4);
    float Xr[4] = {0.f,0.f,0.f,0.f}, Xi[4] = {0.f,0.f,0.f,0.f};
    for (int n2 = 0; n2 < 256; n2 += 4) {
        #pragma unroll
        for (int c = 0; c < 4; ++c) {
            float2 t = Ts[n2 + c];
            Xr[c] += t.x * er[c] - t.y * ei[c];
            Xi[c] += t.x * ei[c] + t.y * er[c];
            float nr = er[c] * c4 - ei[c] * s4;
            ei[c]    = er[c] * s4 + ei[c] * c4;
            er[c] = nr;
        }
    }
    const float inv = 5.5242717280199030e-3f;   // 1/sqrt(32768)
    float xr = (Xr[0] + Xr[1]) + (Xr[2] + Xr[3]);
    float xi = (Xi[0] + Xi[1]) + (Xi[2] + Xi[3]);
    float2* Co = (float2*)C + (size_t)sig * NBINS;
    Co[k1 + 128 * k2] = make_float2(xr * inv, xi * inv);
}

// ---------------------------------------------------------------------------
// Band synthesis — quarter-band decimation (proven r11)
__global__ __launch_bounds__(256) void k_synthA(
    const float* __restrict__ C, float* __restrict__ G)
{
    const int tid = threadIdx.x;
    const int sig = blockIdx.y;
    const int bix = 63 - blockIdx.x;
    const int band = (bix == 0) ? 0 : (32 - __clz(bix));
    const int lbx  = (band == 0) ? 0 : (bix - (1 << (band - 1)));
    const int s    = 512 << band;
    const int m1sh = band_M1sh(band);
    const int lsh  = band_Lsh(band);
    const int m2sh = band_M2sh(band);
    const int M2   = 1 << m2sh;
    const int L    = 1 << lsh;
    const int L4   = L >> 2;
    const int a    = (band == 0) ? 0 : (128 << band);
    const int tix  = lbx * 256 + tid;
    const int j1lo = (lbx * 256) >> (lsh - 2);
    int j1cnt = 256 >> (lsh - 2);
    if (j1cnt > (1 << m1sh)) j1cnt = 1 << m1sh;
    __shared__ float2 Ds[256];
    const float2* D = (const float2*)C + (size_t)sig * NBINS + a;
    for (int i = tid; i < (j1cnt << m2sh); i += 256) {
        int j1o = i >> m2sh, j2 = i & (M2 - 1);
        Ds[i] = D[(j1lo + j1o) + (j2 << m1sh)];
    }
    __syncthreads();
    if (tix >= (128 << band)) return;
    const int j1o = (tix >> (lsh - 2)) - j1lo;
    const int m   = tix & (L4 - 1);
    const float2* Dj = Ds + (j1o << m2sh);
    float e0r = 1.f, e0i = 0.f, e1r, e1i, sr, si;
    sincosf(TWO_PI * (float)m / (float)L, &e1i, &e1r);
    sincosf(TWO_PI * (float)(2 * m) / (float)L, &si, &sr);
    float ar[4] = {0.f,0.f,0.f,0.f}, ai[4] = {0.f,0.f,0.f,0.f};
    for (int j2 = 0; j2 < M2; j2 += 4) {
        {   float2 d = Dj[j2];
            float tr = d.x * e0r - d.y * e0i, ti = d.x * e0i + d.y * e0r;
            ar[0] += tr; ai[0] += ti; ar[1] += tr; ai[1] += ti;
            ar[2] += tr; ai[2] += ti; ar[3] += tr; ai[3] += ti;
            float nr = e0r * sr - e0i * si; e0i = e0r * si + e0i * sr; e0r = nr;
        }
        {   float2 d = Dj[j2 + 1];
            float tr = d.x * e1r - d.y * e1i, ti = d.x * e1i + d.y * e1r;
            ar[0] += tr; ai[0] += ti;
            ar[1] -= ti; ai[1] += tr;
            ar[2] -= tr; ai[2] -= ti;
            ar[3] += ti; ai[3] -= tr;
            float nr = e1r * sr - e1i * si; e1i = e1r * si + e1i * sr; e1r = nr;
        }
        {   float2 d = Dj[j2 + 2];
            float tr = d.x * e0r - d.y * e0i, ti = d.x * e0i + d.y * e0r;
            ar[0] += tr; ai[0] += ti;
            ar[1] -= tr; ai[1] -= ti;
            ar[2] += tr; ai[2] += ti;
            ar[3] -= tr; ai[3] -= ti;
            float nr = e0r * sr - e0i * si; e0i = e0r * si + e0i * sr; e0r = nr;
        }
        {   float2 d = Dj[j2 + 3];
            float tr = d.x * e1r - d.y * e1i, ti = d.x * e1i + d.y * e1r;
            ar[0] += tr; ai[0] += ti;
            ar[1] += ti; ai[1] -= tr;
            ar[2] -= tr; ai[2] -= ti;
            ar[3] -= ti; ai[3] += tr;
            float nr = e1r * sr - e1i * si; e1i = e1r * si + e1i * sr; e1r = nr;
        }
    }
    const float sc = 2.f * rsqrtf((float)s);
    float2* Go = (float2*)G + (size_t)sig * 65024 + 512 * ((1 << band) - 1);
    const int base = ((tix >> (lsh - 2)) << lsh) + m;
    #pragma unroll
    for (int q = 0; q < 4; ++q)
        Go[base + q * L4] = make_float2(ar[q] * sc, ai[q] * sc);
}

__global__ __launch_bounds__(256) void k_synthB(
    const float* __restrict__ C, const float* __restrict__ G,
    float* __restrict__ bands)
{
    const int tid = threadIdx.x;
    const int sig = blockIdx.y;
    const int bix = 63 - blockIdx.x;
    const int band = (bix == 0) ? 0 : (32 - __clz(bix));
    const int lbx  = (band == 0) ? 0 : (bix - (1 << (band - 1)));
    const int s    = 512 << band;
    const int M1   = 1 << band_M1sh(band);
    const int lsh  = band_Lsh(band);
    const int n    = lbx * 256 + tid;
    const int s4   = s >> 2;
    if (n >= s4) return;
    const int m    = n & ((1 << lsh) - 1);
    const float2* Gi = (const float2*)G + (size_t)sig * 65024 + 512 * ((1 << band) - 1);
    float e0r = 1.f, e0i = 0.f, e1r, e1i, sr, si;
    sincosf(TWO_PI * (float)n / (float)s, &e1i, &e1r);
    sincosf(TWO_PI * (float)(2 * n) / (float)s, &si, &sr);
    float zr[4] = {0.f,0.f,0.f,0.f}, zi[4] = {0.f,0.f,0.f,0.f};
    for (int j1 = 0; j1 < M1; j1 += 4) {
        {   float2 g = Gi[((j1 + 0) << lsh) + m];
            float tr = g.x * e0r - g.y * e0i, ti = g.x * e0i + g.y * e0r;
            zr[0] += tr; zi[0] += ti; zr[1] += tr; zi[1] += ti;
            zr[2] += tr; zi[2] += ti; zr[3] += tr; zi[3] += ti;
            float nr = e0r * sr - e0i * si; e0i = e0r * si + e0i * sr; e0r = nr;
        }
        {   float2 g = Gi[((j1 + 1) << lsh) + m];
            float tr = g.x * e1r - g.y * e1i, ti = g.x * e1i + g.y * e1r;
            zr[0] += tr; zi[0] += ti;
            zr[1] -= ti; zi[1] += tr;
            zr[2] -= tr; zi[2] -= ti;
            zr[3] += ti; zi[3] -= tr;
            float nr = e1r * sr - e1i * si; e1i = e1r * si + e1i * sr; e1r = nr;
        }
        {   float2 g = Gi[((j1 + 2) << lsh) + m];
            float tr = g.x * e0r - g.y * e0i, ti = g.x * e0i + g.y * e0r;
            zr[0] += tr; zi[0] += ti;
            zr[1] -= tr; zi[1] -= ti;
            zr[2] += tr; zi[2] += ti;
            zr[3] -= tr; zi[3] -= ti;
            float nr = e0r * sr - e0i * si; e0i = e0r * si + e0i * sr; e0r = nr;
        }
        {   float2 g = Gi[((j1 + 3) << lsh) + m];
            float tr = g.x * e1r - g.y * e1i, ti = g.x * e1i + g.y * e1r;
            zr[0] += tr; zi[0] += ti;
            zr[1] += ti; zi[1] -= tr;
            zr[2] -= tr; zi[2] -= ti;
            zr[3] -= ti; zi[3] += tr;
            float nr = e1r * sr - e1i * si; e1i = e1r * si + e1i * sr; e1r = nr;
        }
    }
    const int poff = 64 * (band + 1) + 512 * ((1 << band) - 1);
    float* bo = bands + (size_t)sig * BAND_STRIDE + poff;
    if (band == 0) {
        const float dc = C[(size_t)sig * NBINS * 2] * 0.04419417382415922f;
        #pragma unroll
        for (int q = 0; q < 4; ++q) bo[n + q * s4] = zr[q] - dc;
    } else {
        #pragma unroll
        for (int q = 0; q < 4; ++q) {
            float val;
            switch (n & 3) {
                case 0:  val =  zr[q]; break;
                case 1:  val = -zi[q]; break;
                case 2:  val = -zr[q]; break;
                default: val =  zi[q]; break;
            }
            bo[n + q * s4] = val;
        }
    }
}

// ---------------------------------------------------------------------------
// K3: MFMA conv + fused segment-max pooling (proven r8, bit-exact)
__global__ __launch_bounds__(256) void k_conv(
    const float* __restrict__ bands,
    const __hip_bfloat16* __restrict__ filters,
    float* __restrict__ segG)
{
    const int tid  = threadIdx.x;
    const int sig  = blockIdx.y;
    const int c    = blockIdx.x;               // 0..126
    const int band = 31 - __clz(c + 1);
    const int cidx = c + 1 - (1 << band);
    const int poff = 64 * (band + 1) + 512 * ((1 << band) - 1);
    const float* bp = bands + (size_t)sig * BAND_STRIDE + poff + cidx * 512;

    __shared__ __align__(16) __hip_bfloat16 xr[8][584];
    __shared__ float segP[64 * 4];

    for (int i = tid; i < 576; i += 256) {
        __hip_bfloat16 b = __float2bfloat16(bp[511 - i]);
        #pragma unroll
        for (int p = 0; p < 8; ++p) {
            int idx = i - p;
            if (idx >= 0) xr[p][idx] = b;
        }
    }
    __syncthreads();

    const int tl   = tid & 15;
    const int quad = (tid >> 4) & 3;
    const int wave = tid >> 6;

    bf16x8 bf0[4], bf1[4];
    #pragma unroll
    for (int ft = 0; ft < 4; ++ft) {
        const __hip_bfloat16* fp = filters + ((ft * 16 + tl) * 64 + quad * 8);
        bf0[ft] = *(const bf16x8*)(fp);
        bf1[ft] = *(const bf16x8*)(fp + 32);
    }

    int s0 = 511 - wave * 128 - tl + 8 * quad;
    const __hip_bfloat16* xp = &xr[0][0] + (s0 & 7) * 584 + (s0 & ~7);

    const int spc = 512 >> (2 + band);
    float* segO = segG + (size_t)(sig * NBANDS + band) * 64 * 128 + cidx * spc;

    const float NEG = -3.4e38f;
    float run0 = NEG, run1 = NEG, run2 = NEG, run3 = NEG;
    const int per = (band >= 2) ? (1 << (band - 2)) : 1;

    for (int it = 0; it < 8; ++it) {
        const int t0 = wave * 128 + it * 16;
        bf16x8 a0 = *(const bf16x8*)(xp);
        bf16x8 a1 = *(const bf16x8*)(xp + 32);
        xp -= 16;
        f32x4 ac0 = {0.f,0.f,0.f,0.f}, ac1 = ac0, ac2 = ac0, ac3 = ac0;
        ac0 = __builtin_amdgcn_mfma_f32_16x16x32_bf16(a0, bf0[0], ac0, 0, 0, 0);
        ac0 = __builtin_amdgcn_mfma_f32_16x16x32_bf16(a1, bf1[0], ac0, 0, 0, 0);
        ac1 = __builtin_amdgcn_mfma_f32_16x16x32_bf16(a0, bf0[1], ac1, 0, 0, 0);
        ac1 = __builtin_amdgcn_mfma_f32_16x16x32_bf16(a1, bf1[1], ac1, 0, 0, 0);
        ac2 = __builtin_amdgcn_mfma_f32_16x16x32_bf16(a0, bf0[2], ac2, 0, 0, 0);
        ac2 = __builtin_amdgcn_mfma_f32_16x16x32_bf16(a1, bf1[2], ac2, 0, 0, 0);
        ac3 = __builtin_amdgcn_mfma_f32_16x16x32_bf16(a0, bf0[3], ac3, 0, 0, 0);
        ac3 = __builtin_amdgcn_mfma_f32_16x16x32_bf16(a1, bf1[3], ac3, 0, 0, 0);
        float m0 = fmaxf(fmaxf(ac0[0], ac0[1]), fmaxf(ac0[2], ac0[3]));
        float m1 = fmaxf(fmaxf(ac1[0], ac1[1]), fmaxf(ac1[2], ac1[3]));
        float m2 = fmaxf(fmaxf(ac2[0], ac2[1]), fmaxf(ac2[2], ac2[3]));
        float m3 = fmaxf(fmaxf(ac3[0], ac3[1]), fmaxf(ac3[2], ac3[3]));
        if (band == 0) {
            int sb = (t0 >> 2) + quad;
            segO[(tl     ) * 128 + sb] = m0;
            segO[(tl + 16) * 128 + sb] = m1;
            segO[(tl + 32) * 128 + sb] = m2;
            segO[(tl + 48) * 128 + sb] = m3;
        } else if (band == 1) {
            m0 = fmaxf(m0, __shfl_xor(m0, 16));
            m1 = fmaxf(m1, __shfl_xor(m1, 16));
            m2 = fmaxf(m2, __shfl_xor(m2, 16));
            m3 = fmaxf(m3, __shfl_xor(m3, 16));
            if ((quad & 1) == 0) {
                int sb = (t0 >> 3) + (quad >> 1);
                segO[(tl     ) * 128 + sb] = m0;
                segO[(tl + 16) * 128 + sb] = m1;
                segO[(tl + 32) * 128 + sb] = m2;
                segO[(tl + 48) * 128 + sb] = m3;
            }
        } else {
            m0 = fmaxf(m0, __shfl_xor(m0, 16)); m0 = fmaxf(m0, __shfl_xor(m0, 32));
            m1 = fmaxf(m1, __shfl_xor(m1, 16)); m1 = fmaxf(m1, __shfl_xor(m1, 32));
            m2 = fmaxf(m2, __shfl_xor(m2, 16)); m2 = fmaxf(m2, __shfl_xor(m2, 32));
            m3 = fmaxf(m3, __shfl_xor(m3, 16)); m3 = fmaxf(m3, __shfl_xor(m3, 32));
            run0 = fmaxf(run0, m0); run1 = fmaxf(run1, m1);
            run2 = fmaxf(run2, m2); run3 = fmaxf(run3, m3);
            if (((it + 1) & (per - 1)) == 0) {
                int sb = t0 >> (2 + band);
                float rv = quad == 0 ? run0 : quad == 1 ? run1
                         : quad == 2 ? run2 : run3;
                segO[(tl + 16 * quad) * 128 + sb] = rv;
                run0 = NEG; run1 = NEG; run2 = NEG; run3 = NEG;
            }
        }
    }
    if (band == 6) {
        float rv = quad == 0 ? run0 : quad == 1 ? run1
                 : quad == 2 ? run2 : run3;
        segP[(tl + 16 * quad) * 4 + wave] = rv;
        __syncthreads();
        if (tid < 128) {
            int f = tid & 63, sg = tid >> 6;
            segO[f * 128 + sg] =
                fmaxf(segP[f * 4 + 2 * sg], segP[f * 4 + 2 * sg + 1]);
        }
    }
}

// ---------------------------------------------------------------------------
// K4: pool + top-128 via radix select + small bitonic sort (proven r9)
__global__ __launch_bounds__(256) void k_topk(
    const float* __restrict__ segG,
    float* __restrict__ topv, int* __restrict__ topi)
{
    const int tid = threadIdx.x;
    const int band = blockIdx.x, sig = blockIdx.y;
    const float* segB = segG + (size_t)(sig * NBANDS + band) * 64 * 128;

    __shared__ unsigned hist[256];
    __shared__ unsigned scan[256];
    __shared__ unsigned long long list[512];
    __shared__ int sh_B, sh_nA, sh_cnt, sh_num;

    unsigned long long kk[16];
    #pragma unroll
    for (int q = 0; q < 16; ++q) {
        int i = q * 256 + tid;
        int f = i >> 6, t = i & 63;
        const float* sg = segB + f * 128;
        float m = fmaxf(sg[2 * t], sg[2 * t + 1]);
        if (t > 0)  m = fmaxf(m, sg[2 * t - 1]);
        if (t < 63) m = fmaxf(m, sg[2 * t + 2]);
        kk[q] = ((unsigned long long)encf(m) << 32) | (unsigned)(4095 - i);
    }

    int shift = 56;
    unsigned long long prefix = 0;
    int nA = 0;
    for (int lev = 0; lev < 8; ++lev) {
        hist[tid] = 0;
        __syncthreads();
        #pragma unroll
        for (int q = 0; q < 16; ++q) {
            bool inpre = (lev == 0) || ((kk[q] >> (shift + 8)) == prefix);
            if (inpre) atomicAdd(&hist[(unsigned)((kk[q] >> shift) & 255u)], 1u);
        }
        __syncthreads();
        scan[tid] = hist[tid];
        __syncthreads();
        for (int off = 1; off < 256; off <<= 1) {
            unsigned v = scan[tid] + ((tid + off < 256) ? scan[tid + off] : 0u);
            __syncthreads();
            scan[tid] = v;
            __syncthreads();
        }
        {
            unsigned ge = (unsigned)nA + scan[tid];
            unsigned gt = (unsigned)nA + ((tid < 255) ? scan[tid + 1] : 0u);
            if (ge >= 128u && gt < 128u) {
                sh_B = tid; sh_nA = (int)gt; sh_cnt = (int)hist[tid];
            }
        }
        __syncthreads();
        prefix = (prefix << 8) | (unsigned)sh_B;
        nA = sh_nA;
        if (nA + sh_cnt <= 511 || shift == 0) break;
        shift -= 8;
        __syncthreads();
    }

    list[tid] = 0ull; list[tid + 256] = 0ull;
    if (tid == 0) sh_num = 0;
    __syncthreads();
    #pragma unroll
    for (int q = 0; q < 16; ++q) {
        if ((kk[q] >> shift) >= prefix) {
            int p = atomicAdd(&sh_num, 1);
            if (p < 512) list[p] = kk[q];
        }
    }
    __syncthreads();

    for (int k = 2; k <= 512; k <<= 1) {
        for (int j = k >> 1; j > 0; j >>= 1) {
            for (int w = tid; w < 512; w += 256) {
                int l = w ^ j;
                if (l > w) {
                    unsigned long long av = list[w], bv = list[l];
                    bool up = ((w & k) == 0);
                    if ((av > bv) == up) { list[w] = bv; list[l] = av; }
                }
            }
            __syncthreads();
        }
    }
    if (tid < K_TOP) {
        unsigned long long key = list[511 - tid];
        const size_t ob = ((size_t)sig * NBANDS + band) * K_TOP + tid;
        topv[ob] = decf((unsigned)(key >> 32));
        topi[ob] = 4095 - (int)(key & 0xFFFFFFFFu);
    }
}

// ---------------------------------------------------------------------------
// K5: loss partial sums + counter-elected FINALIZE (merged k_final).
__global__ __launch_bounds__(256) void k_loss(
    const float* __restrict__ topv, const int* __restrict__ topi,
    const __hip_bfloat16* __restrict__ PT, const __hip_bfloat16* __restrict__ PF,
    float* __restrict__ accum, int* __restrict__ counter,
    const float* __restrict__ C, const float* __restrict__ bands,
    const float* __restrict__ segG, unsigned* __restrict__ out)
{
    const int tid = threadIdx.x;
    const int band = blockIdx.x, b = blockIdx.y;
    const size_t bt = ((size_t)b * NBANDS + band) * K_TOP;
    const size_t br = ((size_t)(8 + b) * NBANDS + band) * K_TOP;
    float sum = 0.f;
    for (int k = 0; k < K_TOP; ++k) {
        float vt = topv[bt + k]; int it = topi[bt + k];
        float vr = topv[br + k]; int ir = topi[br + k];
        if (tid < 128) {
            float a = vt * bf2f(PT[(it & 63) * 128 + tid]);
            float c = vr * bf2f(PT[(ir & 63) * 128 + tid]);
            sum += fabsf(a - c);
        } else {
            int j = tid - 128;
            float a = bf2f(PF[(it >> 6) * 128 + j]);
            float c = bf2f(PF[(ir >> 6) * 128 + j]);
            sum += fabsf(a - c);
        }
    }
    __shared__ float red[256];
    __shared__ int amLast;
    red[tid] = sum;
    __syncthreads();
    for (int ofs = 128; ofs > 0; ofs >>= 1) {
        if (tid < ofs) red[tid] += red[tid + ofs];
        __syncthreads();
    }
    if (tid == 0) {
        atomicAdd(accum, red[0]);
        __threadfence();
        amLast = (atomicAdd(counter, 1) == NBANDS * 8 - 1);
    }
    __syncthreads();
    if (!amLast) return;
    __threadfence();

    // ---- finalize (canary + dual-format store, proven r4) ----
    float s1 = 0.f, s2 = 0.f, s3 = 0.f, s4 = 0.f;
    for (int i = tid; i < 32768; i += 256) s1 += fabsf(C[i]);
    for (int i = tid; i < 512;   i += 256) s2 += fabsf(bands[64 + i]);
    for (int i = tid; i < 4096;  i += 256) s3 += fabsf(segG[i]);
    for (int i = tid; i < 128;   i += 256) s4 += fabsf(topv[i]);
    __shared__ float r1[256], r2[256], r3[256], r4[256];
    r1[tid] = s1; r2[tid] = s2; r3[tid] = s3; r4[tid] = s4;
    __syncthreads();
    for (int ofs = 128; ofs > 0; ofs >>= 1) {
        if (tid < ofs) {
            r1[tid] += r1[tid + ofs]; r2[tid] += r2[tid + ofs];
            r3[tid] += r3[tid + ofs]; r4[tid] += r4[tid + ofs];
        }
        __syncthreads();
    }
    if (tid == 0) {
        float L = atomicAdd(accum, 0.f) * (1.0f / 1835008.0f);
        unsigned lu = __float_as_uint(L);
        bool isnanL = ((lu & 0x7F800000u) == 0x7F800000u) && (lu & 0x007FFFFFu);
        float code;
        if      (r1[0] < 1e-3f)  code = 100.f;
        else if (r2[0] < 1e-6f)  code = 200.f;
        else if (r3[0] < 1e-6f)  code = 300.f;
        else if (r4[0] < 1e-9f)  code = 350.f;
        else if (isnanL)         code = 500.f;
        else if (L == 0.f)       code = 400.f;
        else if (fabsf(L) < 1e-6f) code = 600.f;
        else                     code = L;
        unsigned fb = __float_as_uint(code);
        unsigned hb = (fb + 0x7FFFu + ((fb >> 16) & 1u)) >> 16;
        out[0] = (hb << 16) | hb;
    }
}

// ---------------------------------------------------------------------------
extern "C" void kernel_launch(void* const* d_in, const int* in_sizes, int n_in,
                              void* d_out, int out_size, void* d_ws, size_t ws_size,
                              hipStream_t stream)
{
    float* C      = (float*)d_ws;                          // 524288 f
    float* bands  = C + (size_t)NSIG * NBINS * 2;          // 1047552 f
    float* segG   = bands + (size_t)NSIG * BAND_STRIDE;    // 917504 f
    float* topv   = segG + (size_t)NSIG * NBANDS * 64 * 128; // 14336 f
    int*   topi   = (int*)(topv + (size_t)NSIG * NBANDS * K_TOP);
    float* accum  = (float*)(topi + (size_t)NSIG * NBANDS * K_TOP);
    int*   counter= (int*)(accum + 1);
    __hip_bfloat16* staged = (__hip_bfloat16*)(accum + 4);  // 16B-aligned
    float* TG = (float*)(staged + SST_TOT);   // T and G alias (T dead before G)
    float* T  = TG;
    float* G  = TG;

    const __hip_bfloat16* fst = staged + SST_F;
    const __hip_bfloat16* pts = staged + SST_PT;
    const __hip_bfloat16* pfs = staged + SST_PF;

    k_stage  <<<dim3(SST_TOT / 256 + 1), 256, 0, stream>>>(
                 d_in[0], d_in[2], d_in[3], d_in[4], staged, bands, accum, counter);
    k_fwd1   <<<dim3(2, NSIG),       256, 0, stream>>>(d_in[0], d_in[1], T);
    k_fwd2   <<<dim3(128, NSIG),     128, 0, stream>>>(T, C);
    k_synthA <<<dim3(64, NSIG),      256, 0, stream>>>(C, G);
    k_synthB <<<dim3(64, NSIG),      256, 0, stream>>>(C, G, bands);
    k_conv   <<<dim3(127, NSIG),     256, 0, stream>>>(bands, fst, segG);
    k_topk   <<<dim3(NBANDS, NSIG),  256, 0, stream>>>(segG, topv, topi);
    k_loss   <<<dim3(NBANDS, 8),     256, 0, stream>>>(topv, topi, pts, pfs,
                 accum, counter, C, bands, segG, (unsigned*)d_out);
}

// Round 13
// 207.476 us; speedup vs baseline: 1.3069x; 1.3069x over previous
//
#include <hip/hip_runtime.h>
#include <hip/hip_bf16.h>

#define N_SAMP    32768
#define NBINS     16384
#define NSIG      16
#define NBANDS    7
#define K_TOP     128
// padded per-signal band buffer: 64 zero-floats of guard before each band
#define BAND_STRIDE 65472   // 448 pad + 65024 payload

// staged bf16 layout (small): [filters 4096 | PT 8192 | PF 8192]
#define SST_F   0
#define SST_PT  4096
#define SST_PF  12288
#define SST_TOT 20480

#define TWO_PI 6.283185307179586f

typedef __attribute__((ext_vector_type(8))) short bf16x8;
typedef __attribute__((ext_vector_type(4))) float f32x4;

__device__ __forceinline__ float bf2f(__hip_bfloat16 v) { return __bfloat162float(v); }

__device__ __forceinline__ unsigned encf(float f) {
    unsigned u = __float_as_uint(f);
    return (u & 0x80000000u) ? ~u : (u | 0x80000000u);
}
__device__ __forceinline__ float decf(unsigned u) {
    return __uint_as_float((u & 0x80000000u) ? (u ^ 0x80000000u) : ~u);
}

__device__ __forceinline__ int band_M1sh(int b) { return b < 3 ? 4 : (b < 4 ? 5 : 6); }
__device__ __forceinline__ int band_Lsh(int b) {
    return b == 0 ? 5 : (b == 1 ? 6 : (b < 5 ? 7 : (b == 5 ? 8 : 9)));
}
__device__ __forceinline__ int band_M2sh(int b) {
    return b < 2 ? 4 : (b < 5 ? 5 : (b == 5 ? 6 : 7));
}

// ---------------------------------------------------------------------------
// K_stage (small): stage filters/PT/PF to bf16; tail block zeroes guards +
// accum + counter. Per-block dtype detect (proven r7).
__global__ __launch_bounds__(256) void k_stage(
    const void* __restrict__ t, const void* __restrict__ f,
    const void* __restrict__ pt, const void* __restrict__ pf,
    __hip_bfloat16* __restrict__ staged,
    float* __restrict__ bands, float* __restrict__ accum,
    int* __restrict__ counter)
{
    const int tid = threadIdx.x;
    const int bx  = blockIdx.x;
    if (bx == SST_TOT / 256) {                 // init block
        for (int i = tid; i < NSIG * 448; i += 256) {
            int sig = i / 448, rem = i - sig * 448;
            int g = rem >> 6, j = rem & 63;
            int off = 64 * g + 512 * ((1 << g) - 1);
            bands[(size_t)sig * BAND_STRIDE + off + j] = 0.f;
        }
        if (tid == 0) { accum[0] = 0.f; counter[0] = 0; }
        return;
    }
    float pv = bf2f(((const __hip_bfloat16*)t)[tid & 63]);
    int bad = (fabsf(pv) > 1e8f) || (pv != pv);
    const int isf32 = (__ballot(bad) != 0ull);
    const int id = bx * 256 + tid;
    const void* src; int idx;
    if (id < SST_PT)      { src = f;  idx = id; }
    else if (id < SST_PF) { src = pt; idx = id - SST_PT; }
    else                  { src = pf; idx = id - SST_PF; }
    float v = isf32 ? ((const float*)src)[idx]
                    : bf2f(((const __hip_bfloat16*)src)[idx]);
    staged[id] = __float2bfloat16(v);
}

// ---------------------------------------------------------------------------
// K_fwd1 — MFMA, spill-free restructure of r12 (which PASSED numerically).
// Grid (4, NSIG): blockIdx.x bit0 = n2-half, bit1 = k1-group (64 rows).
// Each wave owns 16 k1 rows -> live A-frags = 16 bf16x8 (64 VGPR), no spill.
// W128 twiddles from an LDS table (no sincosf in the A-build).
__global__ __launch_bounds__(256) void k_fwd1(
    const void* __restrict__ tgt, const void* __restrict__ rec,
    float* __restrict__ T)
{
    const int tid   = threadIdx.x;
    const int sig   = blockIdx.y;
    const int nbase = (blockIdx.x & 1) * 128;  // n2 half
    const int kgrp  = (blockIdx.x >> 1) * 64;  // k1 group base
    __shared__ __align__(16) __hip_bfloat16 xT[128][136];  // [n2-local][n1]
    __shared__ float ct[128], st[128];

    if (tid < 128) {
        float sv, cv;
        sincosf(TWO_PI * (float)tid * (1.f / 128.f), &sv, &cv);
        ct[tid] = cv; st[tid] = sv;
    }

    float pv = bf2f(((const __hip_bfloat16*)tgt)[tid & 63]);
    int bad = (fabsf(pv) > 1e8f) || (pv != pv);
    const int isf32 = (__ballot(bad) != 0ull);
    const void* xsrc = (sig < 8) ? tgt : rec;
    const int soff = (sig & 7) * N_SAMP;

    // stage transpose: row rloc = n2-local, thread covers one n1 half
    const int rloc = tid & 127;
    const int chb  = (tid >> 7) * 64;
    for (int c8 = 0; c8 < 64; c8 += 8) {
        union { bf16x8 v; __hip_bfloat16 h[8]; } u;
        #pragma unroll
        for (int uu = 0; uu < 8; ++uu) {
            int n1 = chb + c8 + uu;
            int gi = soff + n1 * 256 + nbase + rloc;
            float xv = isf32 ? ((const float*)xsrc)[gi]
                             : bf2f(((const __hip_bfloat16*)xsrc)[gi]);
            u.h[uu] = __float2bfloat16(xv);
        }
        *(bf16x8*)(&xT[rloc][chb + c8]) = u.v;
    }
    __syncthreads();

    const int tl = tid & 15, quad = (tid >> 4) & 3, w = tid >> 6;
    const int k1 = kgrp + w * 16 + tl;         // A row m = lane&15
    bf16x8 Arh[4], Arl[4], Aih[4], Ail[4];
    #pragma unroll
    for (int ki = 0; ki < 4; ++ki) {
        union { bf16x8 v; __hip_bfloat16 h[8]; } rh, rl, ih, il;
        #pragma unroll
        for (int j = 0; j < 8; ++j) {
            int n1 = ki * 32 + quad * 8 + j;
            int tt = (k1 * n1) & 127;
            float wre = ct[tt], wim = -st[tt]; // e^{-ia}
            __hip_bfloat16 h1 = __float2bfloat16(wre);
            rh.h[j] = h1;
            rl.h[j] = __float2bfloat16(wre - bf2f(h1));
            __hip_bfloat16 h2 = __float2bfloat16(wim);
            ih.h[j] = h2;
            il.h[j] = __float2bfloat16(wim - bf2f(h2));
        }
        Arh[ki] = rh.v; Arl[ki] = rl.v; Aih[ki] = ih.v; Ail[ki] = il.v;
    }

    float2* To = (float2*)T + (size_t)sig * 128 * 256;
    const int mk = kgrp + w * 16 + quad * 4;   // D row = quad*4+reg
    for (int ni = 0; ni < 8; ++ni) {
        bf16x8 B[4];
        #pragma unroll
        for (int ki = 0; ki < 4; ++ki)         // B[k=n1][n=n2]: b128, aligned
            B[ki] = *(const bf16x8*)(&xT[ni * 16 + tl][ki * 32 + quad * 8]);
        f32x4 aR = {0.f,0.f,0.f,0.f}, aI = {0.f,0.f,0.f,0.f};
        #pragma unroll
        for (int ki = 0; ki < 4; ++ki) {
            aR = __builtin_amdgcn_mfma_f32_16x16x32_bf16(Arh[ki], B[ki], aR, 0, 0, 0);
            aR = __builtin_amdgcn_mfma_f32_16x16x32_bf16(Arl[ki], B[ki], aR, 0, 0, 0);
            aI = __builtin_amdgcn_mfma_f32_16x16x32_bf16(Aih[ki], B[ki], aI, 0, 0, 0);
            aI = __builtin_amdgcn_mfma_f32_16x16x32_bf16(Ail[ki], B[ki], aI, 0, 0, 0);
        }
        const int n2 = nbase + ni * 16 + tl;
        #pragma unroll
        for (int rg = 0; rg < 4; ++rg) {
            int k1e = mk + rg;
            float sv, cv;                      // e^{-i th}: Tr=ar*cv+ai*sv
            sincosf((TWO_PI / 32768.f) * (float)(k1e * n2), &sv, &cv);
            float Tr = aR[rg] * cv + aI[rg] * sv;
            float Ti = aI[rg] * cv - aR[rg] * sv;
            To[(size_t)k1e * 256 + n2] = make_float2(Tr, Ti);
        }
    }
}

// Step2 with 4 independent rotation chains (proven r10)
__global__ __launch_bounds__(128) void k_fwd2(
    const float* __restrict__ T, float* __restrict__ C)
{
    const int k2  = threadIdx.x;              // < 128
    const int k1  = blockIdx.x;
    const int sig = blockIdx.y;
    __shared__ float2 Ts[256];
    const float2* Tin = (const float2*)T + ((size_t)sig * 128 + k1) * 256;
    for (int i = k2; i < 256; i += 128) Ts[i] = Tin[i];
    __syncthreads();
    float er[4], ei[4];
    #pragma unroll
    for (int c = 0; c < 4; ++c) {
        float sv, cv;
        sincosf(-TWO_PI * (float)((c * k2) & 255) * (1.f / 256.f), &sv, &cv);
        er[c] = cv; ei[c] = sv;
    }
    float s4, c4;
    sincosf(-TWO_PI * (float)((4 * k2) & 255) * (1.f / 256.f), &s4, &c4);
    float Xr[4] = {0.f,0.f,0.f,0.f}, Xi[4] = {0.f,0.f,0.f,0.f};
    for (int n2 = 0; n2 < 256; n2 += 4) {
        #pragma unroll
        for (int c = 0; c < 4; ++c) {
            float2 t = Ts[n2 + c];
            Xr[c] += t.x * er[c] - t.y * ei[c];
            Xi[c] += t.x * ei[c] + t.y * er[c];
            float nr = er[c] * c4 - ei[c] * s4;
            ei[c]    = er[c] * s4 + ei[c] * c4;
            er[c] = nr;
        }
    }
    const float inv = 5.5242717280199030e-3f;   // 1/sqrt(32768)
    float xr = (Xr[0] + Xr[1]) + (Xr[2] + Xr[3]);
    float xi = (Xi[0] + Xi[1]) + (Xi[2] + Xi[3]);
    float2* Co = (float2*)C + (size_t)sig * NBINS;
    Co[k1 + 128 * k2] = make_float2(xr * inv, xi * inv);
}

// ---------------------------------------------------------------------------
// Band synthesis — quarter-band decimation (proven r11)
__global__ __launch_bounds__(256) void k_synthA(
    const float* __restrict__ C, float* __restrict__ G)
{
    const int tid = threadIdx.x;
    const int sig = blockIdx.y;
    const int bix = 63 - blockIdx.x;
    const int band = (bix == 0) ? 0 : (32 - __clz(bix));
    const int lbx  = (band == 0) ? 0 : (bix - (1 << (band - 1)));
    const int s    = 512 << band;
    const int m1sh = band_M1sh(band);
    const int lsh  = band_Lsh(band);
    const int m2sh = band_M2sh(band);
    const int M2   = 1 << m2sh;
    const int L    = 1 << lsh;
    const int L4   = L >> 2;
    const int a    = (band == 0) ? 0 : (128 << band);
    const int tix  = lbx * 256 + tid;
    const int j1lo = (lbx * 256) >> (lsh - 2);
    int j1cnt = 256 >> (lsh - 2);
    if (j1cnt > (1 << m1sh)) j1cnt = 1 << m1sh;
    __shared__ float2 Ds[256];
    const float2* D = (const float2*)C + (size_t)sig * NBINS + a;
    for (int i = tid; i < (j1cnt << m2sh); i += 256) {
        int j1o = i >> m2sh, j2 = i & (M2 - 1);
        Ds[i] = D[(j1lo + j1o) + (j2 << m1sh)];
    }
    __syncthreads();
    if (tix >= (128 << band)) return;
    const int j1o = (tix >> (lsh - 2)) - j1lo;
    const int m   = tix & (L4 - 1);
    const float2* Dj = Ds + (j1o << m2sh);
    float e0r = 1.f, e0i = 0.f, e1r, e1i, sr, si;
    sincosf(TWO_PI * (float)m / (float)L, &e1i, &e1r);
    sincosf(TWO_PI * (float)(2 * m) / (float)L, &si, &sr);
    float ar[4] = {0.f,0.f,0.f,0.f}, ai[4] = {0.f,0.f,0.f,0.f};
    for (int j2 = 0; j2 < M2; j2 += 4) {
        {   float2 d = Dj[j2];
            float tr = d.x * e0r - d.y * e0i, ti = d.x * e0i + d.y * e0r;
            ar[0] += tr; ai[0] += ti; ar[1] += tr; ai[1] += ti;
            ar[2] += tr; ai[2] += ti; ar[3] += tr; ai[3] += ti;
            float nr = e0r * sr - e0i * si; e0i = e0r * si + e0i * sr; e0r = nr;
        }
        {   float2 d = Dj[j2 + 1];
            float tr = d.x * e1r - d.y * e1i, ti = d.x * e1i + d.y * e1r;
            ar[0] += tr; ai[0] += ti;
            ar[1] -= ti; ai[1] += tr;
            ar[2] -= tr; ai[2] -= ti;
            ar[3] += ti; ai[3] -= tr;
            float nr = e1r * sr - e1i * si; e1i = e1r * si + e1i * sr; e1r = nr;
        }
        {   float2 d = Dj[j2 + 2];
            float tr = d.x * e0r - d.y * e0i, ti = d.x * e0i + d.y * e0r;
            ar[0] += tr; ai[0] += ti;
            ar[1] -= tr; ai[1] -= ti;
            ar[2] += tr; ai[2] += ti;
            ar[3] -= tr; ai[3] -= ti;
            float nr = e0r * sr - e0i * si; e0i = e0r * si + e0i * sr; e0r = nr;
        }
        {   float2 d = Dj[j2 + 3];
            float tr = d.x * e1r - d.y * e1i, ti = d.x * e1i + d.y * e1r;
            ar[0] += tr; ai[0] += ti;
            ar[1] += ti; ai[1] -= tr;
            ar[2] -= tr; ai[2] -= ti;
            ar[3] -= ti; ai[3] += tr;
            float nr = e1r * sr - e1i * si; e1i = e1r * si + e1i * sr; e1r = nr;
        }
    }
    const float sc = 2.f * rsqrtf((float)s);
    float2* Go = (float2*)G + (size_t)sig * 65024 + 512 * ((1 << band) - 1);
    const int base = ((tix >> (lsh - 2)) << lsh) + m;
    #pragma unroll
    for (int q = 0; q < 4; ++q)
        Go[base + q * L4] = make_float2(ar[q] * sc, ai[q] * sc);
}

__global__ __launch_bounds__(256) void k_synthB(
    const float* __restrict__ C, const float* __restrict__ G,
    float* __restrict__ bands)
{
    const int tid = threadIdx.x;
    const int sig = blockIdx.y;
    const int bix = 63 - blockIdx.x;
    const int band = (bix == 0) ? 0 : (32 - __clz(bix));
    const int lbx  = (band == 0) ? 0 : (bix - (1 << (band - 1)));
    const int s    = 512 << band;
    const int M1   = 1 << band_M1sh(band);
    const int lsh  = band_Lsh(band);
    const int n    = lbx * 256 + tid;
    const int s4   = s >> 2;
    if (n >= s4) return;
    const int m    = n & ((1 << lsh) - 1);
    const float2* Gi = (const float2*)G + (size_t)sig * 65024 + 512 * ((1 << band) - 1);
    float e0r = 1.f, e0i = 0.f, e1r, e1i, sr, si;
    sincosf(TWO_PI * (float)n / (float)s, &e1i, &e1r);
    sincosf(TWO_PI * (float)(2 * n) / (float)s, &si, &sr);
    float zr[4] = {0.f,0.f,0.f,0.f}, zi[4] = {0.f,0.f,0.f,0.f};
    for (int j1 = 0; j1 < M1; j1 += 4) {
        {   float2 g = Gi[((j1 + 0) << lsh) + m];
            float tr = g.x * e0r - g.y * e0i, ti = g.x * e0i + g.y * e0r;
            zr[0] += tr; zi[0] += ti; zr[1] += tr; zi[1] += ti;
            zr[2] += tr; zi[2] += ti; zr[3] += tr; zi[3] += ti;
            float nr = e0r * sr - e0i * si; e0i = e0r * si + e0i * sr; e0r = nr;
        }
        {   float2 g = Gi[((j1 + 1) << lsh) + m];
            float tr = g.x * e1r - g.y * e1i, ti = g.x * e1i + g.y * e1r;
            zr[0] += tr; zi[0] += ti;
            zr[1] -= ti; zi[1] += tr;
            zr[2] -= tr; zi[2] -= ti;
            zr[3] += ti; zi[3] -= tr;
            float nr = e1r * sr - e1i * si; e1i = e1r * si + e1i * sr; e1r = nr;
        }
        {   float2 g = Gi[((j1 + 2) << lsh) + m];
            float tr = g.x * e0r - g.y * e0i, ti = g.x * e0i + g.y * e0r;
            zr[0] += tr; zi[0] += ti;
            zr[1] -= tr; zi[1] -= ti;
            zr[2] += tr; zi[2] += ti;
            zr[3] -= tr; zi[3] -= ti;
            float nr = e0r * sr - e0i * si; e0i = e0r * si + e0i * sr; e0r = nr;
        }
        {   float2 g = Gi[((j1 + 3) << lsh) + m];
            float tr = g.x * e1r - g.y * e1i, ti = g.x * e1i + g.y * e1r;
            zr[0] += tr; zi[0] += ti;
            zr[1] += ti; zi[1] -= tr;
            zr[2] -= tr; zi[2] -= ti;
            zr[3] -= ti; zi[3] += tr;
            float nr = e1r * sr - e1i * si; e1i = e1r * si + e1i * sr; e1r = nr;
        }
    }
    const int poff = 64 * (band + 1) + 512 * ((1 << band) - 1);
    float* bo = bands + (size_t)sig * BAND_STRIDE + poff;
    if (band == 0) {
        const float dc = C[(size_t)sig * NBINS * 2] * 0.04419417382415922f;
        #pragma unroll
        for (int q = 0; q < 4; ++q) bo[n + q * s4] = zr[q] - dc;
    } else {
        #pragma unroll
        for (int q = 0; q < 4; ++q) {
            float val;
            switch (n & 3) {
                case 0:  val =  zr[q]; break;
                case 1:  val = -zi[q]; break;
                case 2:  val = -zr[q]; break;
                default: val =  zi[q]; break;
            }
            bo[n + q * s4] = val;
        }
    }
}

// ---------------------------------------------------------------------------
// K3: MFMA conv + fused segment-max pooling (proven r8, bit-exact)
__global__ __launch_bounds__(256) void k_conv(
    const float* __restrict__ bands,
    const __hip_bfloat16* __restrict__ filters,
    float* __restrict__ segG)
{
    const int tid  = threadIdx.x;
    const int sig  = blockIdx.y;
    const int c    = blockIdx.x;               // 0..126
    const int band = 31 - __clz(c + 1);
    const int cidx = c + 1 - (1 << band);
    const int poff = 64 * (band + 1) + 512 * ((1 << band) - 1);
    const float* bp = bands + (size_t)sig * BAND_STRIDE + poff + cidx * 512;

    __shared__ __align__(16) __hip_bfloat16 xr[8][584];
    __shared__ float segP[64 * 4];

    for (int i = tid; i < 576; i += 256) {
        __hip_bfloat16 b = __float2bfloat16(bp[511 - i]);
        #pragma unroll
        for (int p = 0; p < 8; ++p) {
            int idx = i - p;
            if (idx >= 0) xr[p][idx] = b;
        }
    }
    __syncthreads();

    const int tl   = tid & 15;
    const int quad = (tid >> 4) & 3;
    const int wave = tid >> 6;

    bf16x8 bf0[4], bf1[4];
    #pragma unroll
    for (int ft = 0; ft < 4; ++ft) {
        const __hip_bfloat16* fp = filters + ((ft * 16 + tl) * 64 + quad * 8);
        bf0[ft] = *(const bf16x8*)(fp);
        bf1[ft] = *(const bf16x8*)(fp + 32);
    }

    int s0 = 511 - wave * 128 - tl + 8 * quad;
    const __hip_bfloat16* xp = &xr[0][0] + (s0 & 7) * 584 + (s0 & ~7);

    const int spc = 512 >> (2 + band);
    float* segO = segG + (size_t)(sig * NBANDS + band) * 64 * 128 + cidx * spc;

    const float NEG = -3.4e38f;
    float run0 = NEG, run1 = NEG, run2 = NEG, run3 = NEG;
    const int per = (band >= 2) ? (1 << (band - 2)) : 1;

    for (int it = 0; it < 8; ++it) {
        const int t0 = wave * 128 + it * 16;
        bf16x8 a0 = *(const bf16x8*)(xp);
        bf16x8 a1 = *(const bf16x8*)(xp + 32);
        xp -= 16;
        f32x4 ac0 = {0.f,0.f,0.f,0.f}, ac1 = ac0, ac2 = ac0, ac3 = ac0;
        ac0 = __builtin_amdgcn_mfma_f32_16x16x32_bf16(a0, bf0[0], ac0, 0, 0, 0);
        ac0 = __builtin_amdgcn_mfma_f32_16x16x32_bf16(a1, bf1[0], ac0, 0, 0, 0);
        ac1 = __builtin_amdgcn_mfma_f32_16x16x32_bf16(a0, bf0[1], ac1, 0, 0, 0);
        ac1 = __builtin_amdgcn_mfma_f32_16x16x32_bf16(a1, bf1[1], ac1, 0, 0, 0);
        ac2 = __builtin_amdgcn_mfma_f32_16x16x32_bf16(a0, bf0[2], ac2, 0, 0, 0);
        ac2 = __builtin_amdgcn_mfma_f32_16x16x32_bf16(a1, bf1[2], ac2, 0, 0, 0);
        ac3 = __builtin_amdgcn_mfma_f32_16x16x32_bf16(a0, bf0[3], ac3, 0, 0, 0);
        ac3 = __builtin_amdgcn_mfma_f32_16x16x32_bf16(a1, bf1[3], ac3, 0, 0, 0);
        float m0 = fmaxf(fmaxf(ac0[0], ac0[1]), fmaxf(ac0[2], ac0[3]));
        float m1 = fmaxf(fmaxf(ac1[0], ac1[1]), fmaxf(ac1[2], ac1[3]));
        float m2 = fmaxf(fmaxf(ac2[0], ac2[1]), fmaxf(ac2[2], ac2[3]));
        float m3 = fmaxf(fmaxf(ac3[0], ac3[1]), fmaxf(ac3[2], ac3[3]));
        if (band == 0) {
            int sb = (t0 >> 2) + quad;
            segO[(tl     ) * 128 + sb] = m0;
            segO[(tl + 16) * 128 + sb] = m1;
            segO[(tl + 32) * 128 + sb] = m2;
            segO[(tl + 48) * 128 + sb] = m3;
        } else if (band == 1) {
            m0 = fmaxf(m0, __shfl_xor(m0, 16));
            m1 = fmaxf(m1, __shfl_xor(m1, 16));
            m2 = fmaxf(m2, __shfl_xor(m2, 16));
            m3 = fmaxf(m3, __shfl_xor(m3, 16));
            if ((quad & 1) == 0) {
                int sb = (t0 >> 3) + (quad >> 1);
                segO[(tl     ) * 128 + sb] = m0;
                segO[(tl + 16) * 128 + sb] = m1;
                segO[(tl + 32) * 128 + sb] = m2;
                segO[(tl + 48) * 128 + sb] = m3;
            }
        } else {
            m0 = fmaxf(m0, __shfl_xor(m0, 16)); m0 = fmaxf(m0, __shfl_xor(m0, 32));
            m1 = fmaxf(m1, __shfl_xor(m1, 16)); m1 = fmaxf(m1, __shfl_xor(m1, 32));
            m2 = fmaxf(m2, __shfl_xor(m2, 16)); m2 = fmaxf(m2, __shfl_xor(m2, 32));
            m3 = fmaxf(m3, __shfl_xor(m3, 16)); m3 = fmaxf(m3, __shfl_xor(m3, 32));
            run0 = fmaxf(run0, m0); run1 = fmaxf(run1, m1);
            run2 = fmaxf(run2, m2); run3 = fmaxf(run3, m3);
            if (((it + 1) & (per - 1)) == 0) {
                int sb = t0 >> (2 + band);
                float rv = quad == 0 ? run0 : quad == 1 ? run1
                         : quad == 2 ? run2 : run3;
                segO[(tl + 16 * quad) * 128 + sb] = rv;
                run0 = NEG; run1 = NEG; run2 = NEG; run3 = NEG;
            }
        }
    }
    if (band == 6) {
        float rv = quad == 0 ? run0 : quad == 1 ? run1
                 : quad == 2 ? run2 : run3;
        segP[(tl + 16 * quad) * 4 + wave] = rv;
        __syncthreads();
        if (tid < 128) {
            int f = tid & 63, sg = tid >> 6;
            segO[f * 128 + sg] =
                fmaxf(segP[f * 4 + 2 * sg], segP[f * 4 + 2 * sg + 1]);
        }
    }
}

// ---------------------------------------------------------------------------
// K4: pool + top-128 via radix select + small bitonic sort (proven r9)
__global__ __launch_bounds__(256) void k_topk(
    const float* __restrict__ segG,
    float* __restrict__ topv, int* __restrict__ topi)
{
    const int tid = threadIdx.x;
    const int band = blockIdx.x, sig = blockIdx.y;
    const float* segB = segG + (size_t)(sig * NBANDS + band) * 64 * 128;

    __shared__ unsigned hist[256];
    __shared__ unsigned scan[256];
    __shared__ unsigned long long list[512];
    __shared__ int sh_B, sh_nA, sh_cnt, sh_num;

    unsigned long long kk[16];
    #pragma unroll
    for (int q = 0; q < 16; ++q) {
        int i = q * 256 + tid;
        int f = i >> 6, t = i & 63;
        const float* sg = segB + f * 128;
        float m = fmaxf(sg[2 * t], sg[2 * t + 1]);
        if (t > 0)  m = fmaxf(m, sg[2 * t - 1]);
        if (t < 63) m = fmaxf(m, sg[2 * t + 2]);
        kk[q] = ((unsigned long long)encf(m) << 32) | (unsigned)(4095 - i);
    }

    int shift = 56;
    unsigned long long prefix = 0;
    int nA = 0;
    for (int lev = 0; lev < 8; ++lev) {
        hist[tid] = 0;
        __syncthreads();
        #pragma unroll
        for (int q = 0; q < 16; ++q) {
            bool inpre = (lev == 0) || ((kk[q] >> (shift + 8)) == prefix);
            if (inpre) atomicAdd(&hist[(unsigned)((kk[q] >> shift) & 255u)], 1u);
        }
        __syncthreads();
        scan[tid] = hist[tid];
        __syncthreads();
        for (int off = 1; off < 256; off <<= 1) {
            unsigned v = scan[tid] + ((tid + off < 256) ? scan[tid + off] : 0u);
            __syncthreads();
            scan[tid] = v;
            __syncthreads();
        }
        {
            unsigned ge = (unsigned)nA + scan[tid];
            unsigned gt = (unsigned)nA + ((tid < 255) ? scan[tid + 1] : 0u);
            if (ge >= 128u && gt < 128u) {
                sh_B = tid; sh_nA = (int)gt; sh_cnt = (int)hist[tid];
            }
        }
        __syncthreads();
        prefix = (prefix << 8) | (unsigned)sh_B;
        nA = sh_nA;
        if (nA + sh_cnt <= 511 || shift == 0) break;
        shift -= 8;
        __syncthreads();
    }

    list[tid] = 0ull; list[tid + 256] = 0ull;
    if (tid == 0) sh_num = 0;
    __syncthreads();
    #pragma unroll
    for (int q = 0; q < 16; ++q) {
        if ((kk[q] >> shift) >= prefix) {
            int p = atomicAdd(&sh_num, 1);
            if (p < 512) list[p] = kk[q];
        }
    }
    __syncthreads();

    for (int k = 2; k <= 512; k <<= 1) {
        for (int j = k >> 1; j > 0; j >>= 1) {
            for (int w = tid; w < 512; w += 256) {
                int l = w ^ j;
                if (l > w) {
                    unsigned long long av = list[w], bv = list[l];
                    bool up = ((w & k) == 0);
                    if ((av > bv) == up) { list[w] = bv; list[l] = av; }
                }
            }
            __syncthreads();
        }
    }
    if (tid < K_TOP) {
        unsigned long long key = list[511 - tid];
        const size_t ob = ((size_t)sig * NBANDS + band) * K_TOP + tid;
        topv[ob] = decf((unsigned)(key >> 32));
        topi[ob] = 4095 - (int)(key & 0xFFFFFFFFu);
    }
}

// ---------------------------------------------------------------------------
// K5: loss with LDS-prefetched indices (breaks the dependent-load chain) +
// counter-elected finalize (value-level codes only; scans dropped).
__global__ __launch_bounds__(256) void k_loss(
    const float* __restrict__ topv, const int* __restrict__ topi,
    const __hip_bfloat16* __restrict__ PT, const __hip_bfloat16* __restrict__ PF,
    float* __restrict__ accum, int* __restrict__ counter,
    unsigned* __restrict__ out)
{
    const int tid = threadIdx.x;
    const int band = blockIdx.x, b = blockIdx.y;
    const size_t bt = ((size_t)b * NBANDS + band) * K_TOP;
    const size_t br = ((size_t)(8 + b) * NBANDS + band) * K_TOP;
    __shared__ float vT[128], vR[128];
    __shared__ int   iT[128], iR[128];
    if (tid < 128) { vT[tid] = topv[bt + tid]; iT[tid] = topi[bt + tid]; }
    else { int j = tid - 128; vR[j] = topv[br + j]; iR[j] = topi[br + j]; }
    __syncthreads();
    float sum = 0.f;
    if (tid < 128) {
        #pragma unroll 4
        for (int k = 0; k < K_TOP; ++k) {
            float a = vT[k] * bf2f(PT[(iT[k] & 63) * 128 + tid]);
            float c = vR[k] * bf2f(PT[(iR[k] & 63) * 128 + tid]);
            sum += fabsf(a - c);
        }
    } else {
        const int j = tid - 128;
        #pragma unroll 4
        for (int k = 0; k < K_TOP; ++k) {
            float a = bf2f(PF[(iT[k] >> 6) * 128 + j]);
            float c = bf2f(PF[(iR[k] >> 6) * 128 + j]);
            sum += fabsf(a - c);
        }
    }
    __shared__ float red[256];
    __shared__ int amLast;
    red[tid] = sum;
    __syncthreads();
    for (int ofs = 128; ofs > 0; ofs >>= 1) {
        if (tid < ofs) red[tid] += red[tid + ofs];
        __syncthreads();
    }
    if (tid == 0) {
        atomicAdd(accum, red[0]);
        __threadfence();
        amLast = (atomicAdd(counter, 1) == NBANDS * 8 - 1);
    }
    __syncthreads();
    if (!amLast) return;
    if (tid == 0) {
        __threadfence();
        float L = atomicAdd(accum, 0.f) * (1.0f / 1835008.0f);
        unsigned lu = __float_as_uint(L);
        bool isnanL = ((lu & 0x7F800000u) == 0x7F800000u) && (lu & 0x007FFFFFu);
        float code;
        if      (isnanL)           code = 500.f;
        else if (L == 0.f)         code = 400.f;
        else if (fabsf(L) < 1e-6f) code = 600.f;
        else                       code = L;
        unsigned fb = __float_as_uint(code);
        unsigned hb = (fb + 0x7FFFu + ((fb >> 16) & 1u)) >> 16;
        out[0] = (hb << 16) | hb;    // dual-format store (proven r4)
    }
}

// ---------------------------------------------------------------------------
extern "C" void kernel_launch(void* const* d_in, const int* in_sizes, int n_in,
                              void* d_out, int out_size, void* d_ws, size_t ws_size,
                              hipStream_t stream)
{
    float* C      = (float*)d_ws;                          // 524288 f
    float* bands  = C + (size_t)NSIG * NBINS * 2;          // 1047552 f
    float* segG   = bands + (size_t)NSIG * BAND_STRIDE;    // 917504 f
    float* topv   = segG + (size_t)NSIG * NBANDS * 64 * 128; // 14336 f
    int*   topi   = (int*)(topv + (size_t)NSIG * NBANDS * K_TOP);
    float* accum  = (float*)(topi + (size_t)NSIG * NBANDS * K_TOP);
    int*   counter= (int*)(accum + 1);
    __hip_bfloat16* staged = (__hip_bfloat16*)(accum + 4);  // 16B-aligned
    float* TG = (float*)(staged + SST_TOT);   // T and G alias (T dead before G)
    float* T  = TG;
    float* G  = TG;

    const __hip_bfloat16* fst = staged + SST_F;
    const __hip_bfloat16* pts = staged + SST_PT;
    const __hip_bfloat16* pfs = staged + SST_PF;

    k_stage  <<<dim3(SST_TOT / 256 + 1), 256, 0, stream>>>(
                 d_in[0], d_in[2], d_in[3], d_in[4], staged, bands, accum, counter);
    k_fwd1   <<<dim3(4, NSIG),       256, 0, stream>>>(d_in[0], d_in[1], T);
    k_fwd2   <<<dim3(128, NSIG),     128, 0, stream>>>(T, C);
    k_synthA <<<dim3(64, NSIG),      256, 0, stream>>>(C, G);
    k_synthB <<<dim3(64, NSIG),      256, 0, stream>>>(C, G, bands);
    k_conv   <<<dim3(127, NSIG),     256, 0, stream>>>(bands, fst, segG);
    k_topk   <<<dim3(NBANDS, NSIG),  256, 0, stream>>>(segG, topv, topi);
    k_loss   <<<dim3(NBANDS, 8),     256, 0, stream>>>(topv, topi, pts, pfs,
                 accum, counter, (unsigned*)d_out);
}